// Round 6
// baseline (91.071 us; speedup 1.0000x reference)
//
#include <hip/hip_runtime.h>
#include <math.h>

constexpr int NQ  = 12;
constexpr int NS  = 1 << NQ;   // 4096 amplitudes
constexpr int NL  = 4;
constexpr int BLK = 512;       // 8 waves -> 2 waves/SIMD at 1 block/CU
constexpr int R   = 8;         // amplitudes per thread
constexpr float PI_F = 3.14159265358979323846f;

// amp index i bit layout:
//   bit11 = tid8, bit10 = tid7, bit0 = tid6   (wave bits; G = tid>>6 = (b11,b10,b0))
//   bits 9..4 = tid bits 5..0                  (lane bits)
//   bits 3..1 = r bits 2..0                    (register bits)

typedef float2 c32;

__device__ __forceinline__ c32 cmul(c32 a, c32 b) {
    return make_float2(a.x * b.x - a.y * b.y, a.x * b.y + a.y * b.x);
}
__device__ __forceinline__ c32 cmad(c32 a, c32 b, c32 c) {
    return make_float2(fmaf(a.x, b.x, fmaf(-a.y, b.y, c.x)),
                       fmaf(a.x, b.y, fmaf( a.y, b.x, c.y)));
}

// ---------------- VALU lane-exchange primitives ----------------
// row_shr:N = lane i <- i-N, row_shl:N = lane i <- i+N (verified R5).
template<int CTRL>
__device__ __forceinline__ float dppmov(float v) {
    return __int_as_float(__builtin_amdgcn_mov_dpp(__float_as_int(v), CTRL, 0xF, 0xF, false));
}
__device__ __forceinline__ float dppx4(float v) {
    int s = __float_as_int(v);
    int o = __builtin_amdgcn_update_dpp(s, s, 0x104, 0xF, 0x5, false); // row_shl:4 -> banks 0,2
    o     = __builtin_amdgcn_update_dpp(o, s, 0x114, 0xF, 0xA, false); // row_shr:4 -> banks 1,3
    return __int_as_float(o);
}

#if __has_builtin(__builtin_amdgcn_permlane16_swap)
#define HAVE_PL16 1
#endif
#if __has_builtin(__builtin_amdgcn_permlane32_swap)
#define HAVE_PL32 1
#endif

template<int M>
__device__ __forceinline__ float lanex(float v, int tid) {
    if constexpr (M == 1)  return dppmov<0xB1>(v);        // quad_perm [1,0,3,2]
    else if constexpr (M == 2)  return dppmov<0x4E>(v);   // quad_perm [2,3,0,1]
    else if constexpr (M == 4)  return dppx4(v);
    else if constexpr (M == 8)  return dppmov<0x128>(v);  // row_ror:8
    else if constexpr (M == 16) {
#ifdef HAVE_PL16
        auto r = __builtin_amdgcn_permlane16_swap(__float_as_int(v), __float_as_int(v), false, false);
        return __int_as_float((tid & 16) ? r[0] : r[1]);
#else
        return __shfl_xor(v, 16, 64);
#endif
    } else { // M == 32
#ifdef HAVE_PL32
        auto r = __builtin_amdgcn_permlane32_swap(__float_as_int(v), __float_as_int(v), false, false);
        return __int_as_float((tid & 32) ? r[0] : r[1]);
#else
        return __shfl_xor(v, 32, 64);
#endif
    }
}
template<int M>
__device__ __forceinline__ c32 cx(c32 v, int tid) {
    return make_float2(lanex<M>(v.x, tid), lanex<M>(v.y, tid));
}

template<int P>
__device__ __forceinline__ void gate_reg(c32* v, c32 U00, c32 U01, c32 U10, c32 U11) {
    #pragma unroll
    for (int r = 0; r < R; ++r)
        if (!(r & (1 << P))) {
            c32 a = v[r], b = v[r | (1 << P)];
            v[r]            = cmad(U01, b, cmul(U00, a));
            v[r | (1 << P)] = cmad(U11, b, cmul(U10, a));
        }
}

template<int M>
__device__ __forceinline__ void gate_lane(c32* v, int tid, c32 U00, c32 U01, c32 U10, c32 U11) {
    const bool hi = tid & M;
    const c32 Ud = hi ? U11 : U00;
    const c32 Uo = hi ? U10 : U01;
    #pragma unroll
    for (int r = 0; r < R; ++r) {
        c32 o = cx<M>(v[r], tid);
        v[r] = cmad(Uo, o, cmul(Ud, v[r]));
    }
}

template<int CM, int TM>
__device__ __forceinline__ void cnot_ll(c32* v, int tid) {
    const bool c_ = tid & CM;
    #pragma unroll
    for (int r = 0; r < R; ++r) {
        c32 o = cx<TM>(v[r], tid);
        if (c_) v[r] = o;
    }
}

template<int PC, int PT>
__device__ __forceinline__ void cnot_rr(c32* v) {
    #pragma unroll
    for (int r = 0; r < R; ++r)
        if ((r & (1 << PC)) && !(r & (1 << PT))) {
            c32 t = v[r]; v[r] = v[r ^ (1 << PT)]; v[r ^ (1 << PT)] = t;
        }
}

__global__ __launch_bounds__(BLK, 2)
void qsim_kernel(const float* __restrict__ x,    // (B,12)
                 const float* __restrict__ w,    // (4,12,3)
                 const float* __restrict__ ent,  // (4,12)
                 float* __restrict__ out)        // (B,12)
{
    __shared__ c32  xbuf[NS];           // 32 KB cross-wave exchange: [r*BLK + tid]
    __shared__ c32  gmat[NL * NQ][4];
    __shared__ c32  uenc[NQ][2];
    __shared__ int  entf[NL * NQ];
    __shared__ float redbuf[8 * NQ];

    const int tid = threadIdx.x;
    const int b   = blockIdx.x;

    if (tid < NL * NQ) {
        float phi = w[tid * 3 + 0], th = w[tid * 3 + 1], om = w[tid * 3 + 2];
        float s, c;   sincosf(0.5f * th, &s, &c);
        float sa, ca; sincosf(0.5f * (phi + om), &sa, &ca);
        float sm, cm; sincosf(0.5f * (phi - om), &sm, &cm);
        gmat[tid][0] = make_float2( c * ca, -c * sa);
        gmat[tid][1] = make_float2(-s * cm, -s * sm);
        gmat[tid][2] = make_float2( s * cm, -s * sm);
        gmat[tid][3] = make_float2( c * ca,  c * sa);
        entf[tid] = ent[tid] > 0.5f;
    }
    if (tid >= 64 && tid < 64 + NQ) {
        int q = tid - 64;
        float xv = x[b * NQ + q];
        float s, c;   sincosf(0.5f * PI_F * xv, &s, &c);
        float zs, zc; sincosf(0.5f * PI_F * xv * xv, &zs, &zc);
        uenc[q][0] = make_float2(c * zc, -c * zs);
        uenc[q][1] = make_float2(s * zc,  s * zs);
    }
    __syncthreads();

    const int lane = tid & 63;
    const int G    = tid >> 6;       // (bit11, bit10, bit0)
    const int t6 = (tid >> 6) & 1, t7 = (tid >> 7) & 1, t8 = (tid >> 8) & 1;

    // ---- encoded product state ----
    // q: 0->b11(t8) 1->b10(t7) 2..7->tid5..0  8..10->r2..0  11->b0(t6)
    c32 A = cmul(uenc[0][t8], uenc[1][t7]);
    A = cmul(A, uenc[2][(tid >> 5) & 1]);
    A = cmul(A, uenc[3][(tid >> 4) & 1]);
    A = cmul(A, uenc[4][(tid >> 3) & 1]);
    A = cmul(A, uenc[5][(tid >> 2) & 1]);
    A = cmul(A, uenc[6][(tid >> 1) & 1]);
    A = cmul(A, uenc[7][tid & 1]);
    A = cmul(A, uenc[11][t6]);
    c32 BC[4];
    #pragma unroll
    for (int k = 0; k < 4; ++k)
        BC[k] = cmul(uenc[9][k >> 1], uenc[10][k & 1]);
    c32 v[R];
    #pragma unroll
    for (int r = 0; r < R; ++r)
        v[r] = cmul(A, cmul(uenc[8][r >> 2], BC[r & 3]));

    // ---- layers ----
    #pragma unroll 1
    for (int layer = 0; layer < NL; ++layer) {
        const int gb = layer * NQ;

        // ===== fused 8x8 gate on amp bits (11,10,0) =====
        // = Rot_q0(b11) ⊗ Rot_q1(b10) ⊗ Rot_q11(b0),
        //   + this layer's CNOT(11,10) as row perm,
        //   + prev layer's CNOT(1,0) and CNOT(0,11) as column perms.
        {
            const c32* Ua = gmat[gb + 0];
            const c32* Ub = gmat[gb + 1];
            const c32* Uc = gmat[gb + 11];
            int gp = G;
            if (entf[gb + 0] && (gp & 4)) gp ^= 2;       // CNOT(11,10) row fold
            const int ar = (gp >> 2) * 2, br = ((gp >> 1) & 1) * 2, cr = (gp & 1) * 2;
            c32 bc[4];
            bc[0] = cmul(Ub[br + 0], Uc[cr + 0]);
            bc[1] = cmul(Ub[br + 0], Uc[cr + 1]);
            bc[2] = cmul(Ub[br + 1], Uc[cr + 0]);
            bc[3] = cmul(Ub[br + 1], Uc[cr + 1]);
            c32 src[8];
            #pragma unroll
            for (int j = 0; j < 8; ++j) src[j] = cmul(Ua[ar + (j >> 2)], bc[j & 3]);

            const bool e110p = (layer > 0) && entf[gb - NQ + 10];  // prev CNOT(1,0)
            const bool e011p = (layer > 0) && entf[gb - NQ + 11];  // prev CNOT(0,11)
            // read index m(j): m=j; if(e011p && j&1) m^=4; if(e110p && p) m^=1  (p = r&1)
            c32 rowE[8], rowO[8];
            #pragma unroll
            for (int j = 0; j < 8; ++j) {
                int mE = (e011p && (j & 1)) ? (j ^ 4) : j;
                int mO = e110p ? (mE ^ 1) : mE;
                rowE[mE] = src[j];
                rowO[mO] = src[j];
            }

            #pragma unroll
            for (int r = 0; r < R; ++r) xbuf[r * BLK + tid] = v[r];
            __syncthreads();
            #pragma unroll
            for (int r = 0; r < R; ++r) {
                const c32* rw = (r & 1) ? rowO : rowE;
                c32 acc = cmul(rw[0], xbuf[r * BLK + lane]);
                #pragma unroll
                for (int m = 1; m < 8; ++m)
                    acc = cmad(rw[m], xbuf[r * BLK + (m << 6) + lane], acc);
                v[r] = acc;
            }
            __syncthreads();
        }

        // ===== lane-bit Rots q=2..7 (bits 9..4 = tid5..0) =====
        { const c32* u = gmat[gb + 2];  gate_lane<32>(v, tid, u[0], u[1], u[2], u[3]); }
        { const c32* u = gmat[gb + 3];  gate_lane<16>(v, tid, u[0], u[1], u[2], u[3]); }
        { const c32* u = gmat[gb + 4];  gate_lane< 8>(v, tid, u[0], u[1], u[2], u[3]); }
        { const c32* u = gmat[gb + 5];  gate_lane< 4>(v, tid, u[0], u[1], u[2], u[3]); }
        { const c32* u = gmat[gb + 6];  gate_lane< 2>(v, tid, u[0], u[1], u[2], u[3]); }
        { const c32* u = gmat[gb + 7];  gate_lane< 1>(v, tid, u[0], u[1], u[2], u[3]); }
        // ===== reg-bit Rots q=8..10 (bits 3..1 = r2..0) =====
        { const c32* u = gmat[gb + 8];  gate_reg<2>(v, u[0], u[1], u[2], u[3]); }
        { const c32* u = gmat[gb + 9];  gate_reg<1>(v, u[0], u[1], u[2], u[3]); }
        { const c32* u = gmat[gb + 10]; gate_reg<0>(v, u[0], u[1], u[2], u[3]); }

        // ===== CNOT chain: q=0 folded above; q=10,11 folded forward =====
        if (entf[gb + 1] && (tid & 128)) {     // (10,9): ctrl b10=tid7, tgt b9=tid5
            #pragma unroll
            for (int r = 0; r < R; ++r) v[r] = cx<32>(v[r], tid);
        }
        if (entf[gb + 2]) cnot_ll<32, 16>(v, tid);   // (9,8)
        if (entf[gb + 3]) cnot_ll<16,  8>(v, tid);   // (8,7)
        if (entf[gb + 4]) cnot_ll< 8,  4>(v, tid);   // (7,6)
        if (entf[gb + 5]) cnot_ll< 4,  2>(v, tid);   // (6,5)
        if (entf[gb + 6]) cnot_ll< 2,  1>(v, tid);   // (5,4)
        if (entf[gb + 7]) {                          // (4,3): ctrl tid0, tgt r bit2
            const bool c_ = tid & 1;
            #pragma unroll
            for (int rl = 0; rl < 4; ++rl) {
                c32 a = v[rl], bb = v[rl | 4];
                v[rl]     = c_ ? bb : a;
                v[rl | 4] = c_ ? a  : bb;
            }
        }
        if (entf[gb + 8]) cnot_rr<2, 1>(v);          // (3,2)
        if (entf[gb + 9]) cnot_rr<1, 0>(v);          // (2,1)
        // q=10 (1,0) and q=11 (0,11): folded into next fused gate / measurement
    }

    // ---- measurement; last layer's CNOT(1,0),(0,11) folded into signs ----
    const bool e110L = entf[(NL - 1) * NQ + 10];
    const bool e011L = entf[(NL - 1) * NQ + 11];

    float pr[R];
    #pragma unroll
    for (int r = 0; r < R; ++r) pr[r] = v[r].x * v[r].x + v[r].y * v[r].y;

    float S = 0.f, T2 = 0.f, T1 = 0.f, T0 = 0.f, acc0 = 0.f, acc11 = 0.f;
    #pragma unroll
    for (int r = 0; r < R; ++r) {
        S  += pr[r];
        T2 += (r & 4) ? -pr[r] : pr[r];
        T1 += (r & 2) ? -pr[r] : pr[r];
        T0 += (r & 1) ? -pr[r] : pr[r];
        const int s0  = t6 ^ (e110L & (r & 1));          // effective amp bit0
        const int s11 = t8 ^ (e011L & s0);               // effective amp bit11
        acc11 += s0  ? -pr[r] : pr[r];
        acc0  += s11 ? -pr[r] : pr[r];
    }

    float contrib[NQ];
    contrib[0]  = acc0;
    contrib[1]  = t7 ? -S : S;
    contrib[2]  = ((tid >> 5) & 1) ? -S : S;
    contrib[3]  = ((tid >> 4) & 1) ? -S : S;
    contrib[4]  = ((tid >> 3) & 1) ? -S : S;
    contrib[5]  = ((tid >> 2) & 1) ? -S : S;
    contrib[6]  = ((tid >> 1) & 1) ? -S : S;
    contrib[7]  = (tid & 1) ? -S : S;
    contrib[8]  = T2;
    contrib[9]  = T1;
    contrib[10] = T0;
    contrib[11] = acc11;

    #pragma unroll
    for (int off = 32; off; off >>= 1) {
        #pragma unroll
        for (int q = 0; q < NQ; ++q) contrib[q] += __shfl_xor(contrib[q], off, 64);
    }
    if ((tid & 63) == 0) {
        const int wv = tid >> 6;
        #pragma unroll
        for (int q = 0; q < NQ; ++q) redbuf[wv * NQ + q] = contrib[q];
    }
    __syncthreads();
    if (tid < NQ) {
        float s = 0.f;
        #pragma unroll
        for (int wv = 0; wv < 8; ++wv) s += redbuf[wv * NQ + tid];
        out[b * NQ + tid] = s;
    }
}

extern "C" void kernel_launch(void* const* d_in, const int* in_sizes, int n_in,
                              void* d_out, int out_size, void* d_ws, size_t ws_size,
                              hipStream_t stream) {
    const float* x   = (const float*)d_in[0];  // (B,12)
    const float* w   = (const float*)d_in[1];  // (4,12,3)
    const float* ent = (const float*)d_in[2];  // (4,12)
    float* out = (float*)d_out;
    const int B = in_sizes[0] / NQ;
    qsim_kernel<<<B, BLK, 0, stream>>>(x, w, ent, out);
}

// Round 7
// 80.554 us; speedup vs baseline: 1.1306x; 1.1306x over previous
//
#include <hip/hip_runtime.h>
#include <math.h>

constexpr int NQ  = 12;
constexpr int NS  = 1 << NQ;   // 4096 amplitudes
constexpr int NL  = 4;
constexpr int BLK = 256;
constexpr int R   = 16;        // amplitudes per thread (reg bits = amp bits 0..3)
constexpr float PI_F = 3.14159265358979323846f;

// amp index i = (tid << 4) | r
//   bits 0..3  : register index r
//   bits 4..9  : lane bits (tid bits 0..5)
//   bits 10..11: wave bits (tid bits 6..7)

typedef float c32 __attribute__((ext_vector_type(2)));   // (re, im) -> v_pk_* math

__device__ __forceinline__ c32 cmul(c32 a, c32 b) {
    c32 t = (c32){-a.y, a.y} * b.yx;
    return (c32){a.x, a.x} * b + t;
}

// broadcast forms of a gate coefficient: out = g.xx*b + g.ny*b.yx  (2 pk ops)
struct cg { c32 xx, ny; };
__device__ __forceinline__ cg mkg(c32 u) {
    cg g; g.xx = (c32){u.x, u.x}; g.ny = (c32){-u.y, u.y}; return g;
}
__device__ __forceinline__ c32 cmulg(cg g, c32 b) {
    return g.xx * b + g.ny * b.yx;
}
__device__ __forceinline__ c32 cmadg(cg g, c32 b, c32 c) {
    return g.xx * b + (g.ny * b.yx + c);
}

// ---------------- VALU lane-exchange primitives ----------------
// row_shr:N = lane i <- i-N, row_shl:N = lane i <- i+N (verified R5).
template<int CTRL>
__device__ __forceinline__ float dppmov(float v) {
    return __int_as_float(__builtin_amdgcn_mov_dpp(__float_as_int(v), CTRL, 0xF, 0xF, false));
}
__device__ __forceinline__ float dppx4(float v) {
    int s = __float_as_int(v);
    int o = __builtin_amdgcn_update_dpp(s, s, 0x104, 0xF, 0x5, false); // row_shl:4 -> banks 0,2
    o     = __builtin_amdgcn_update_dpp(o, s, 0x114, 0xF, 0xA, false); // row_shr:4 -> banks 1,3
    return __int_as_float(o);
}

#if __has_builtin(__builtin_amdgcn_permlane16_swap)
#define HAVE_PL16 1
#endif
#if __has_builtin(__builtin_amdgcn_permlane32_swap)
#define HAVE_PL32 1
#endif

template<int M>
__device__ __forceinline__ float lanex(float v, int tid) {
    if constexpr (M == 1)  return dppmov<0xB1>(v);        // quad_perm [1,0,3,2]
    else if constexpr (M == 2)  return dppmov<0x4E>(v);   // quad_perm [2,3,0,1]
    else if constexpr (M == 4)  return dppx4(v);
    else if constexpr (M == 8)  return dppmov<0x128>(v);  // row_ror:8
    else if constexpr (M == 16) {
#ifdef HAVE_PL16
        auto r = __builtin_amdgcn_permlane16_swap(__float_as_int(v), __float_as_int(v), false, false);
        return __int_as_float((tid & 16) ? r[0] : r[1]);
#else
        return __shfl_xor(v, 16, 64);
#endif
    } else { // M == 32
#ifdef HAVE_PL32
        auto r = __builtin_amdgcn_permlane32_swap(__float_as_int(v), __float_as_int(v), false, false);
        return __int_as_float((tid & 32) ? r[0] : r[1]);
#else
        return __shfl_xor(v, 32, 64);
#endif
    }
}
template<int M>
__device__ __forceinline__ c32 cx(c32 v, int tid) {
    return (c32){lanex<M>(v.x, tid), lanex<M>(v.y, tid)};
}

// ---- single-qubit gate, qubit bit in register index ----
template<int P>
__device__ __forceinline__ void gate_reg(c32* v, c32 U00, c32 U01, c32 U10, c32 U11) {
    const cg g00 = mkg(U00), g01 = mkg(U01), g10 = mkg(U10), g11 = mkg(U11);
    #pragma unroll
    for (int r = 0; r < R; ++r)
        if (!(r & (1 << P))) {
            c32 a = v[r], b = v[r | (1 << P)];
            v[r]            = cmadg(g01, b, cmulg(g00, a));
            v[r | (1 << P)] = cmadg(g11, b, cmulg(g10, a));
        }
}

// ---- single-qubit gate, qubit bit is a lane bit (VALU exchange) ----
template<int M>
__device__ __forceinline__ void gate_lane(c32* v, int tid, c32 U00, c32 U01, c32 U10, c32 U11) {
    const bool hi = tid & M;
    const c32 Ud = hi ? U11 : U00;
    const c32 Uo = hi ? U10 : U01;
    const cg gd = mkg(Ud), go = mkg(Uo);
    #pragma unroll
    for (int r = 0; r < R; ++r) {
        c32 o = cx<M>(v[r], tid);
        v[r] = cmadg(gd, v[r], cmulg(go, o));
    }
}

// ---- CNOT, control+target both lane bits (VALU) ----
template<int CM, int TM>
__device__ __forceinline__ void cnot_ll(c32* v, int tid) {
    const bool c_ = tid & CM;
    #pragma unroll
    for (int r = 0; r < R; ++r) {
        c32 o = cx<TM>(v[r], tid);
        if (c_) v[r] = o;
    }
}

// ---- CNOT, control+target both register bits ----
template<int PC, int PT>
__device__ __forceinline__ void cnot_rr(c32* v) {
    #pragma unroll
    for (int r = 0; r < R; ++r)
        if ((r & (1 << PC)) && !(r & (1 << PT))) {
            c32 t = v[r]; v[r] = v[r ^ (1 << PT)]; v[r ^ (1 << PT)] = t;
        }
}

__global__ __launch_bounds__(BLK, 1)
void qsim_kernel(const float* __restrict__ x,    // (B,12)
                 const float* __restrict__ w,    // (4,12,3)
                 const float* __restrict__ ent,  // (4,12)
                 float* __restrict__ out)        // (B,12)
{
    __shared__ c32  xbuf[NS];           // 32 KB cross-wave exchange
    __shared__ c32  gmat[NL * NQ][4];
    __shared__ c32  uenc[NQ][2];
    __shared__ int  entf[NL * NQ];
    __shared__ float redbuf[4 * NQ];

    const int tid = threadIdx.x;
    const int b   = blockIdx.x;

    if (tid < NL * NQ) {
        float phi = w[tid * 3 + 0], th = w[tid * 3 + 1], om = w[tid * 3 + 2];
        float s, c;   sincosf(0.5f * th, &s, &c);
        float sa, ca; sincosf(0.5f * (phi + om), &sa, &ca);
        float sm, cm; sincosf(0.5f * (phi - om), &sm, &cm);
        gmat[tid][0] = (c32){ c * ca, -c * sa};
        gmat[tid][1] = (c32){-s * cm, -s * sm};
        gmat[tid][2] = (c32){ s * cm, -s * sm};
        gmat[tid][3] = (c32){ c * ca,  c * sa};
        entf[tid] = ent[tid] > 0.5f;
    }
    if (tid >= 64 && tid < 64 + NQ) {
        int q = tid - 64;
        float xv = x[b * NQ + q];
        float s, c;   sincosf(0.5f * PI_F * xv, &s, &c);
        float zs, zc; sincosf(0.5f * PI_F * xv * xv, &zs, &zc);
        uenc[q][0] = (c32){c * zc, -c * zs};
        uenc[q][1] = (c32){s * zc,  s * zs};
    }
    __syncthreads();

    // ---- build encoded product state directly in registers ----
    c32 A = uenc[0][(tid >> 7) & 1];
    #pragma unroll
    for (int q = 1; q < 8; ++q) A = cmul(A, uenc[q][(tid >> (7 - q)) & 1]);
    c32 AP[4], PAB[4];
    #pragma unroll
    for (int j = 0; j < 4; ++j)
        AP[j] = cmul(A, cmul(uenc[8][j >> 1], uenc[9][j & 1]));
    #pragma unroll
    for (int k = 0; k < 4; ++k)
        PAB[k] = cmul(uenc[10][k >> 1], uenc[11][k & 1]);
    c32 v[R];
    #pragma unroll
    for (int r = 0; r < R; ++r) v[r] = cmul(AP[(r >> 2) & 3], PAB[r & 3]);

    const int lane_slot = tid & 63;
    const int g         = tid >> 6;   // quadrant = amp bits (11,10)

    // ---- layers ----
    #pragma unroll 1
    for (int layer = 0; layer < NL; ++layer) {
        const int gb = layer * NQ;

        // ===== fused 4x4 gate on amp bits (11,10) =====
        //   = Rot(bit11) ⊗ Rot(bit10), + this layer's CNOT(11,10) as row perm
        //   + prev layer's CNOT(0,11) as column perm on odd-r amplitudes.
        {
            const c32* Ua = gmat[gb + 0];
            const c32* Ub = gmat[gb + 1];
            const int  gp = (entf[gb + 0] && (g & 2)) ? (g ^ 1) : g;  // CNOT(11,10) fold
            const int  ar = (gp >> 1) * 2, br = (gp & 1) * 2;
            c32 rowE[4];
            rowE[0] = cmul(Ua[ar + 0], Ub[br + 0]);
            rowE[1] = cmul(Ua[ar + 0], Ub[br + 1]);
            rowE[2] = cmul(Ua[ar + 1], Ub[br + 0]);
            rowE[3] = cmul(Ua[ar + 1], Ub[br + 1]);
            const bool pf = (layer > 0) && entf[gb - 1];              // prev CNOT(0,11) fold
            cg gE[4], gO[4];
            #pragma unroll
            for (int j = 0; j < 4; ++j) {
                gE[j] = mkg(rowE[j]);
                gO[j] = mkg(pf ? rowE[j ^ 2] : rowE[j]);
            }

            #pragma unroll
            for (int r = 0; r < R; ++r) xbuf[r * BLK + tid] = v[r];
            __syncthreads();
            #pragma unroll
            for (int r = 0; r < R; ++r) {
                const cg* rw = (r & 1) ? gO : gE;
                c32 acc = cmulg(rw[0], xbuf[r * BLK +   0 + lane_slot]);
                acc     = cmadg(rw[1], xbuf[r * BLK +  64 + lane_slot], acc);
                acc     = cmadg(rw[2], xbuf[r * BLK + 128 + lane_slot], acc);
                acc     = cmadg(rw[3], xbuf[r * BLK + 192 + lane_slot], acc);
                v[r] = acc;
            }
            __syncthreads();
        }

        // ===== Rot gates on lane bits (VALU exchanges) and reg bits =====
        { const c32* u = gmat[gb + 2];  gate_lane<32>(v, tid, u[0], u[1], u[2], u[3]); }
        { const c32* u = gmat[gb + 3];  gate_lane<16>(v, tid, u[0], u[1], u[2], u[3]); }
        { const c32* u = gmat[gb + 4];  gate_lane< 8>(v, tid, u[0], u[1], u[2], u[3]); }
        { const c32* u = gmat[gb + 5];  gate_lane< 4>(v, tid, u[0], u[1], u[2], u[3]); }
        { const c32* u = gmat[gb + 6];  gate_lane< 2>(v, tid, u[0], u[1], u[2], u[3]); }
        { const c32* u = gmat[gb + 7];  gate_lane< 1>(v, tid, u[0], u[1], u[2], u[3]); }
        { const c32* u = gmat[gb + 8];  gate_reg<3>(v, u[0], u[1], u[2], u[3]); }
        { const c32* u = gmat[gb + 9];  gate_reg<2>(v, u[0], u[1], u[2], u[3]); }
        { const c32* u = gmat[gb + 10]; gate_reg<1>(v, u[0], u[1], u[2], u[3]); }
        { const c32* u = gmat[gb + 11]; gate_reg<0>(v, u[0], u[1], u[2], u[3]); }

        // ===== CNOT chain (q=0 folded above; q=11 folded forward) =====
        if (entf[gb + 1] && (tid & 64)) {      // (10,9): ctrl wave bit6, tgt lane bit5
            #pragma unroll
            for (int r = 0; r < R; ++r) v[r] = cx<32>(v[r], tid);
        }
        if (entf[gb + 2]) cnot_ll<32, 16>(v, tid);   // (9,8)
        if (entf[gb + 3]) cnot_ll<16,  8>(v, tid);   // (8,7)
        if (entf[gb + 4]) cnot_ll< 8,  4>(v, tid);   // (7,6)
        if (entf[gb + 5]) cnot_ll< 4,  2>(v, tid);   // (6,5)
        if (entf[gb + 6]) cnot_ll< 2,  1>(v, tid);   // (5,4)
        if (entf[gb + 7]) {                          // (4,3): ctrl lane bit0, tgt reg bit3
            const bool c_ = tid & 1;
            #pragma unroll
            for (int r = 0; r < 8; ++r) {
                c32 a = v[r], bb = v[r | 8];
                v[r]     = c_ ? bb : a;
                v[r | 8] = c_ ? a  : bb;
            }
        }
        if (entf[gb + 8])  cnot_rr<3, 2>(v);         // (3,2)
        if (entf[gb + 9])  cnot_rr<2, 1>(v);         // (2,1)
        if (entf[gb + 10]) cnot_rr<1, 0>(v);         // (1,0)
        // q=11 CNOT(0,11): folded into next fused gate, or into measurement
    }

    // ---- measurement; last layer's CNOT(0,11) folded into q0's sign ----
    // CNOT(0,11): flips amp bit 11 where amp bit0 (= r&1) is 1 -> only the
    // qubit-0 expectation (sign from amp bit 11 = tid7) changes.
    const bool e011L = entf[(NL - 1) * NQ + 11];
    const int  t7    = (tid >> 7) & 1;

    float pr[R];
    #pragma unroll
    for (int r = 0; r < R; ++r) {
        c32 p = v[r] * v[r];
        pr[r] = p.x + p.y;
    }
    float S = 0.f, acc0 = 0.f;
    #pragma unroll
    for (int r = 0; r < R; ++r) {
        S += pr[r];
        const int s11 = t7 ^ (e011L & (r & 1));
        acc0 += s11 ? -pr[r] : pr[r];
    }
    float T[4];
    #pragma unroll
    for (int pb = 0; pb < 4; ++pb) {
        float t = 0.f;
        #pragma unroll
        for (int r = 0; r < R; ++r) t += ((r >> pb) & 1) ? -pr[r] : pr[r];
        T[pb] = t;
    }

    float contrib[NQ];
    contrib[0] = acc0;
    #pragma unroll
    for (int q = 1; q < 8; ++q) contrib[q] = ((tid >> (7 - q)) & 1) ? -S : S;
    contrib[8] = T[3]; contrib[9] = T[2]; contrib[10] = T[1]; contrib[11] = T[0];

    #pragma unroll
    for (int off = 32; off; off >>= 1) {
        #pragma unroll
        for (int q = 0; q < NQ; ++q) contrib[q] += __shfl_xor(contrib[q], off, 64);
    }
    if ((tid & 63) == 0) {
        const int wv = tid >> 6;
        #pragma unroll
        for (int q = 0; q < NQ; ++q) redbuf[wv * NQ + q] = contrib[q];
    }
    __syncthreads();
    if (tid < NQ)
        out[b * NQ + tid] = redbuf[tid] + redbuf[NQ + tid] + redbuf[2 * NQ + tid] + redbuf[3 * NQ + tid];
}

extern "C" void kernel_launch(void* const* d_in, const int* in_sizes, int n_in,
                              void* d_out, int out_size, void* d_ws, size_t ws_size,
                              hipStream_t stream) {
    const float* x   = (const float*)d_in[0];  // (B,12)
    const float* w   = (const float*)d_in[1];  // (4,12,3)
    const float* ent = (const float*)d_in[2];  // (4,12)
    float* out = (float*)d_out;
    const int B = in_sizes[0] / NQ;
    qsim_kernel<<<B, BLK, 0, stream>>>(x, w, ent, out);
}